// Round 5
// baseline (444.389 us; speedup 1.0000x reference)
//
#include <hip/hip_runtime.h>
#include <hip/hip_bf16.h>

#define D 128
#define NBUCK_SHIFT 9
#define PAD_SLACK 2048   // per-bucket overflow slack (needs ~1800 avg)

typedef __bf16 bf16x8 __attribute__((ext_vector_type(8)));
typedef float f32x4 __attribute__((ext_vector_type(4)));
typedef float f32x2 __attribute__((ext_vector_type(2)));
typedef int i32x4 __attribute__((ext_vector_type(4)));
typedef int i32x2 __attribute__((ext_vector_type(2)));
typedef unsigned int u32x4 __attribute__((ext_vector_type(4)));
typedef unsigned short u16x4_t __attribute__((ext_vector_type(4)));
typedef unsigned short u16x8_t __attribute__((ext_vector_type(8)));

__device__ __forceinline__ unsigned short f2b(float f) {
    __hip_bfloat16 h = __float2bfloat16(f);
    return __builtin_bit_cast(unsigned short, h);
}

// accumulate 8 bf16 (as 4 u32) into 4 f32x2 accumulators; f32x2 += invites v_pk_add_f32
__device__ __forceinline__ void acc8(f32x2* acc, u32x4 x) {
#pragma unroll
    for (int r = 0; r < 4; ++r) {
        f32x2 t;
        t[0] = __builtin_bit_cast(float, x[r] << 16);
        t[1] = __builtin_bit_cast(float, x[r] & 0xffff0000u);
        acc[r] += t;
    }
}

// ---------------- CSR build (bucket-local, no per-node global atomics) ----------------
// Phase A: coarse histogram over nbuck (<=256) dst-buckets, LDS-aggregated.
__global__ __launch_bounds__(256) void coarse_hist_kernel(
        const int* __restrict__ dst, int* __restrict__ bco, int E, int nbuck) {
    __shared__ int s[256];
    int t = threadIdx.x;
    s[t] = 0;
    __syncthreads();
    for (int i = blockIdx.x * 256 + t; i < E; i += gridDim.x * 256)
        atomicAdd(&s[dst[i] >> NBUCK_SHIFT], 1);
    __syncthreads();
    if (t < nbuck && s[t] > 0) atomicAdd(&bco[t], s[t]);
}

// Phase B: exclusive scan of bucket counts -> bbase[0..nbuck], bbase[nbuck]=E. One block.
__global__ __launch_bounds__(256) void bucket_scan_kernel(
        const int* __restrict__ bco, int* __restrict__ bbase, int nbuck, int E) {
    __shared__ int s[256];
    int t = threadIdx.x;
    int c = (t < nbuck) ? bco[t] : 0;
    s[t] = c;
    __syncthreads();
    for (int o = 1; o < 256; o <<= 1) {
        int y = (t >= o) ? s[t - o] : 0;
        __syncthreads();
        s[t] += y;
        __syncthreads();
    }
    if (t < nbuck) bbase[t] = s[t] - c;
    if (t == 0) bbase[nbuck] = E;
}

// Phase C: partition edges into dst-bucket-grouped packed records (src<<9 | dst&511).
__global__ __launch_bounds__(256) void bucket_kernel(
        const int* __restrict__ src, const int* __restrict__ dst,
        const int* __restrict__ bbase, int* __restrict__ bcursor,
        unsigned int* __restrict__ pairs, int E, int nbuck) {
    __shared__ int lcnt[256];
    __shared__ int lbase[256];
    int t = threadIdx.x;
    int base = blockIdx.x * 4096;
    if (t < nbuck) lcnt[t] = 0;
    __syncthreads();
    int d[16], s[16];
#pragma unroll
    for (int k = 0; k < 16; ++k) {
        int i = base + t + k * 256;
        if (i < E) {
            d[k] = dst[i];
            s[k] = src[i];
            atomicAdd(&lcnt[d[k] >> NBUCK_SHIFT], 1);
        } else {
            d[k] = -1;
            s[k] = 0;
        }
    }
    __syncthreads();
    if (t < nbuck) {
        int c = lcnt[t];
        int g = (c > 0) ? atomicAdd(&bcursor[t], c) : 0;
        lbase[t] = bbase[t] + g;
        lcnt[t] = 0;
    }
    __syncthreads();
#pragma unroll
    for (int k = 0; k < 16; ++k) {
        if (d[k] >= 0) {
            int b = d[k] >> NBUCK_SHIFT;
            int r = atomicAdd(&lcnt[b], 1);
            pairs[lbase[b] + r] = ((unsigned)s[k] << 9) | ((unsigned)d[k] & 511u);
        }
    }
}

// Phase D: per-bucket LDS histogram + scan.
// rowhead[N][16] = {self, first 15 neighbors, zero-row dummies} as byte offsets (row*256).
// Overflow (deg>15) -> padded CSR windows (rowse = {start,end}, multiple of 4, 16B-aligned).
__global__ __launch_bounds__(1024) void bucket_build_kernel(
        const unsigned int* __restrict__ pairs, const int* __restrict__ bbase,
        i32x2* __restrict__ rowse, int* __restrict__ col, int* __restrict__ rowhead,
        int N, int E) {
    __shared__ int cnt[512];
    __shared__ int off[512];
    int t = threadIdx.x;
    int b = blockIdx.x;
    int s0 = bbase[b], s1 = bbase[b + 1];
    int p0 = ((s0 + 3) & ~3) + b * PAD_SLACK;   // overflow window base (16B aligned)
    if (t < 512) cnt[t] = 0;
    __syncthreads();
    for (int i = s0 + t; i < s1; i += 1024)
        atomicAdd(&cnt[pairs[i] & 511u], 1);
    __syncthreads();
    int deg = (t < 512) ? cnt[t] : 0;
    int ovp = (deg > 15) ? ((deg - 15 + 3) & ~3) : 0;   // padded overflow count
    if (t < 512) off[t] = ovp;
    __syncthreads();
    for (int o = 1; o < 512; o <<= 1) {
        int y = (t < 512 && t >= o) ? off[t - o] : 0;
        __syncthreads();
        if (t < 512) off[t] += y;
        __syncthreads();
    }
    int v0 = b << NBUCK_SHIFT;
    int zoff = N << 8;                          // byte offset of the all-zero row
    if (t < 512) {
        int ex = off[t] - ovp;                  // exclusive overflow prefix
        off[t] = ex;
        cnt[t] = 0;
        int v = v0 + t;
        if (v < N) {
            i32x2 se;
            se[0] = p0 + ex;
            se[1] = p0 + ex + ovp;
            rowse[v] = se;
            int* rhv = rowhead + (size_t)v * 16;
            rhv[0] = v << 8;                    // self-loop slot
            int ninl = deg < 15 ? deg : 15;
            for (int q = 1 + ninl; q < 16; ++q) rhv[q] = zoff;
        }
    }
    __syncthreads();
    for (int i = s0 + t; i < s1; i += 1024) {
        unsigned int p = pairs[i];
        int li = (int)(p & 511u);
        int x = (int)(p >> 9);
        int s = atomicAdd(&cnt[li], 1);
        if (s < 15) rowhead[(size_t)(v0 + li) * 16 + 1 + s] = x << 8;
        else        col[p0 + off[li] + (s - 15)] = x << 8;
    }
    __syncthreads();
    if (t < 512) {
        int cc = cnt[t];                        // == deg
        int ovreal = (cc > 15) ? cc - 15 : 0;
        int base2 = p0 + off[t];
        int endp = base2 + ((ovreal + 3) & ~3);
        for (int q = base2 + ovreal; q < endp; ++q) col[q] = zoff;
    }
}

// ---------------- dtype conversion ----------------
__global__ void f32_to_bf16_kernel(const float4* __restrict__ in, ushort4* __restrict__ out, int n4) {
    int i = blockIdx.x * blockDim.x + threadIdx.x;
    if (i < n4) {
        float4 f = in[i];
        ushort4 o;
        o.x = f2b(f.x); o.y = f2b(f.y); o.z = f2b(f.z); o.w = f2b(f.w);
        out[i] = o;
    }
}

// W[l][k][n] row-major -> frag-blocked bf16 for use as MFMA A-operand (swapped GEMM):
// flat short idx = ((l*32 + nt*4 + kb)*64 + lg*16 + l15)*8 + j holds W[k=kb*32+lg*8+j][n=nt*16+l15]
__global__ void wtrans_kernel(const float* __restrict__ W1, const float* __restrict__ W2,
                              unsigned short* __restrict__ W1L, unsigned short* __restrict__ W2L,
                              int total) {
    int i = blockIdx.x * blockDim.x + threadIdx.x;
    if (i < total) {
        int l = i >> 14;
        int rem = i & 16383;
        int k = rem >> 7;
        int n = rem & 127;
        int nt = n >> 4, l15 = n & 15;
        int kb = k >> 5, lg = (k >> 3) & 3, j = k & 7;
        int o = ((l * 32 + nt * 4 + kb) * 64 + lg * 16 + l15) * 8 + j;
        W1L[o] = f2b(W1[i]);
        W2L[o] = f2b(W2[i]);
    }
}

// ---------------- FUSED layer: persistent blocks, register-resident W ----------------
// Block = 256 threads = 4 waves; grid-strides over 16-node tiles.
// Per wave: its 8 W1 + 8 W2 fragments (for nt = wave*2, wave*2+1) preloaded ONCE into
// 64 VGPRs -> per-tile MLP phase has zero W traffic.
// Phase 1 (agg): wave w aggregates nodes v0+4w..+3 into LDS rstile (row stride 136
//   shorts = 272B -> b128 reads hit exactly 8 words/bank, conflict-minimal).
// Phase 2 (mlp): wave handles its 2 nt quadrants; h1 staged in shared padded buffer
//   (per-wave kb2 = wave regions disjoint).
#define RSTRIDE 136
__global__ __launch_bounds__(256, 4) void fused_kernel(
        const unsigned short* __restrict__ h, const i32x2* __restrict__ rowse,
        const int* __restrict__ col, const i32x4* __restrict__ rowhead,
        const unsigned short* __restrict__ W1L, const unsigned short* __restrict__ W2L,
        const float* __restrict__ b1, const float* __restrict__ b2,
        unsigned short* __restrict__ hOut, float* __restrict__ fOut,
        int mode, int ntiles, int N) {
    __shared__ float b1s[128], b2s[128];
    __shared__ unsigned short rstile[16 * RSTRIDE];
    __shared__ unsigned short h1buf[2560];
    int tid = threadIdx.x;
    if (tid < 128) b1s[tid] = b1[tid];
    else b2s[tid - 128] = b2[tid - 128];
    int wave = tid >> 6, lane = tid & 63;
    int l15 = lane & 15, lg = lane >> 4;

    // ---- preload W fragments for this wave's two nt quadrants (once per block) ----
    bf16x8 w1r[2][4], w2r[2][4];
#pragma unroll
    for (int t = 0; t < 2; ++t) {
        int nt = wave * 2 + t;
#pragma unroll
        for (int kb = 0; kb < 4; ++kb) {
            w1r[t][kb] = *(const bf16x8*)(W1L + ((nt * 4 + kb) * 64 + lane) * 8);
            w2r[t][kb] = *(const bf16x8*)(W2L + ((nt * 4 + kb) * 64 + lane) * 8);
        }
    }

    const char* __restrict__ hb = (const char*)h;

    for (int tile = blockIdx.x; tile < ntiles; tile += gridDim.x) {
        int v0 = tile << 4;

        // ---------- phase 1: aggregation ----------
        {
            int i = lane & 15;           // feature block (16B)
            int j = lane >> 4;           // edge-slot group
            unsigned ioff = (unsigned)i * 16u;
            for (int q = 0; q < 4; ++q) {
                int m = wave * 4 + q;
                int v = v0 + m;
                f32x2 accA[4], accB[4], accC[4], accD[4];
#pragma unroll
                for (int r = 0; r < 4; ++r) {
                    accA[r] = (f32x2){0.f, 0.f};
                    accB[r] = (f32x2){0.f, 0.f};
                    accC[r] = (f32x2){0.f, 0.f};
                    accD[r] = (f32x2){0.f, 0.f};
                }
                if (v < N) {
                    i32x4 c4 = __builtin_nontemporal_load(&rowhead[(size_t)v * 4 + j]);
                    i32x2 se = __builtin_nontemporal_load(&rowse[v]);
                    u32x4 x0 = *(const u32x4*)(hb + ((unsigned)c4[0] + ioff));
                    u32x4 x1 = *(const u32x4*)(hb + ((unsigned)c4[1] + ioff));
                    u32x4 x2 = *(const u32x4*)(hb + ((unsigned)c4[2] + ioff));
                    u32x4 x3 = *(const u32x4*)(hb + ((unsigned)c4[3] + ioff));
                    int e = se[0] + 4 * j;
                    int e1 = se[1];
                    bool have = (e < e1);
                    i32x4 o4;
                    if (have) o4 = __builtin_nontemporal_load((const i32x4*)(col + e));
                    acc8(accA, x0);
                    acc8(accB, x1);
                    acc8(accC, x2);
                    acc8(accD, x3);
                    while (have) {
                        int en = e + 16;
                        bool haven = (en < e1);
                        i32x4 o4n;
                        if (haven) o4n = __builtin_nontemporal_load((const i32x4*)(col + en));
                        u32x4 y0 = *(const u32x4*)(hb + ((unsigned)o4[0] + ioff));
                        u32x4 y1 = *(const u32x4*)(hb + ((unsigned)o4[1] + ioff));
                        u32x4 y2 = *(const u32x4*)(hb + ((unsigned)o4[2] + ioff));
                        u32x4 y3 = *(const u32x4*)(hb + ((unsigned)o4[3] + ioff));
                        acc8(accA, y0);
                        acc8(accB, y1);
                        acc8(accC, y2);
                        acc8(accD, y3);
                        o4 = o4n;
                        e = en;
                        have = haven;
                    }
                }
                unsigned short outv[8];
#pragma unroll
                for (int r = 0; r < 4; ++r) {
                    f32x2 s = (accA[r] + accB[r]) + (accC[r] + accD[r]);
                    float lo = s[0], hi = s[1];
                    lo += __shfl_xor(lo, 16);
                    lo += __shfl_xor(lo, 32);
                    hi += __shfl_xor(hi, 16);
                    hi += __shfl_xor(hi, 32);
                    outv[2 * r] = f2b(lo);
                    outv[2 * r + 1] = f2b(hi);
                }
                if (j == 0) {
                    u16x8_t o;
#pragma unroll
                    for (int r = 0; r < 8; ++r) o[r] = outv[r];
                    *(u16x8_t*)(rstile + m * RSTRIDE + i * 8) = o;
                }
            }
        }
        __syncthreads();

        // ---------- phase 2: 2-GEMM MLP (wave handles nt = wave*2, wave*2+1) ----------
        bf16x8 bfrag[4];
#pragma unroll
        for (int kb = 0; kb < 4; ++kb)
            bfrag[kb] = *(const bf16x8*)(rstile + l15 * RSTRIDE + lg * 8 + kb * 32);

        f32x4 acc[2];
#pragma unroll
        for (int t = 0; t < 2; ++t) acc[t] = (f32x4){0.f, 0.f, 0.f, 0.f};
#pragma unroll
        for (int kb = 0; kb < 4; ++kb)
#pragma unroll
            for (int t = 0; t < 2; ++t)
                acc[t] = __builtin_amdgcn_mfma_f32_16x16x32_bf16(w1r[t][kb], bfrag[kb], acc[t], 0, 0, 0);
#pragma unroll
        for (int t = 0; t < 2; ++t) {
            int nt = wave * 2 + t;
            f32x4 bias = *(const f32x4*)(b1s + nt * 16 + lg * 4);
            int kb2 = nt >> 1;                    // == wave: per-wave disjoint h1 region
            int lgk = (nt & 1) * 2 + (lg >> 1);
            int U = kb2 * 80 + l15 * 5 + lgk;
            u16x4_t o;
#pragma unroll
            for (int r = 0; r < 4; ++r) {
                float x = acc[t][r] + bias[r];
                if (mode == 0) x = fmaxf(x, 0.f);
                o[r] = f2b(x);
            }
            *(u16x4_t*)(h1buf + U * 8 + (lg & 1) * 4) = o;
        }
        __syncthreads();
        bf16x8 bf2[4];
#pragma unroll
        for (int kb = 0; kb < 4; ++kb)
            bf2[kb] = *(const bf16x8*)(h1buf + (kb * 80 + l15 * 5 + lg) * 8);
#pragma unroll
        for (int t = 0; t < 2; ++t) acc[t] = (f32x4){0.f, 0.f, 0.f, 0.f};
#pragma unroll
        for (int kb = 0; kb < 4; ++kb)
#pragma unroll
            for (int t = 0; t < 2; ++t)
                acc[t] = __builtin_amdgcn_mfma_f32_16x16x32_bf16(w2r[t][kb], bf2[kb], acc[t], 0, 0, 0);
        int m = v0 + l15;
        if (m < N) {
#pragma unroll
            for (int t = 0; t < 2; ++t) {
                int nt = wave * 2 + t;
                f32x4 bias = *(const f32x4*)(b2s + nt * 16 + lg * 4);
                int c0 = nt * 16 + lg * 4;
                if (mode == 0) {
                    u16x4_t o;
#pragma unroll
                    for (int r = 0; r < 4; ++r) o[r] = f2b(fmaxf(acc[t][r] + bias[r], 0.f));
                    *(u16x4_t*)(hOut + (size_t)m * D + c0) = o;
                } else {
                    f32x4 o;
#pragma unroll
                    for (int r = 0; r < 4; ++r) o[r] = acc[t][r] + bias[r];
                    *(f32x4*)(fOut + (size_t)m * D + c0) = o;
                }
            }
        }
        __syncthreads();   // protect rstile/h1buf before next tile's writes
    }
}

extern "C" void kernel_launch(void* const* d_in, const int* in_sizes, int n_in,
                              void* d_out, int out_size, void* d_ws, size_t ws_size,
                              hipStream_t stream) {
    const float* feat = (const float*)d_in[0];
    const float* W1 = (const float*)d_in[1];
    const float* b1 = (const float*)d_in[2];
    const float* W2 = (const float*)d_in[3];
    const float* b2 = (const float*)d_in[4];
    const int* src = (const int*)d_in[5];
    const int* dst = (const int*)d_in[6];

    const int N = in_sizes[0] / D;
    const int L = in_sizes[2] / D;
    const int E = in_sizes[5];

    char* w = (char*)d_ws;
    size_t off = 0;
    auto alloc = [&](size_t bytes) {
        void* p = w + off;
        off = (off + bytes + 255) & ~(size_t)255;
        return p;
    };
    // +1 row on h buffers: row N is the all-zero row that dummy (padding) slots read.
    unsigned short* bufA = (unsigned short*)alloc((size_t)(N + 1) * D * 2);
    unsigned short* bufB = (unsigned short*)alloc((size_t)(N + 1) * D * 2);
    unsigned int* pairs = (unsigned int*)alloc((size_t)E * 4);
    int* col = (int*)alloc(((size_t)E + 256 * PAD_SLACK + 16) * 4);
    int* rowhead = (int*)alloc((size_t)N * 16 * 4);
    i32x2* rowse = (i32x2*)alloc((size_t)N * 8);
    int* bco = (int*)alloc(512 * 4);       // bco[256] + bcursor[256]
    int* bcursor = bco + 256;
    int* bbase = (int*)alloc(257 * 4);
    unsigned short* W1L = (unsigned short*)alloc((size_t)L * 16384 * 2);
    unsigned short* W2L = (unsigned short*)alloc((size_t)L * 16384 * 2);

    int nbuck = (N + (1 << NBUCK_SHIFT) - 1) >> NBUCK_SHIFT;

    // CSR build — bucket-local, rowhead + overflow CSR
    hipMemsetAsync(bco, 0, 512 * 4, stream);
    hipMemsetAsync(bufA + (size_t)N * D, 0, D * 2, stream);
    hipMemsetAsync(bufB + (size_t)N * D, 0, D * 2, stream);
    coarse_hist_kernel<<<512, 256, 0, stream>>>(dst, bco, E, nbuck);
    bucket_scan_kernel<<<1, 256, 0, stream>>>(bco, bbase, nbuck, E);
    bucket_kernel<<<(E + 4095) / 4096, 256, 0, stream>>>(src, dst, bbase, bcursor, pairs, E, nbuck);
    bucket_build_kernel<<<nbuck, 1024, 0, stream>>>(pairs, bbase, rowse, col, rowhead, N, E);

    // dtype prep
    int n4 = N * D / 4;
    f32_to_bf16_kernel<<<(n4 + 255) / 256, 256, 0, stream>>>((const float4*)feat, (ushort4*)bufA, n4);
    int wtotal = L * D * D;
    wtrans_kernel<<<(wtotal + 255) / 256, 256, 0, stream>>>(W1, W2, W1L, W2L, wtotal);

    int ntiles = (N + 15) / 16;
    int fgrid = ntiles < 1024 ? ntiles : 1024;
    const unsigned short* hin[3] = {bufA, bufB, bufA};
    unsigned short* hout[3] = {bufB, bufA, nullptr};
    for (int i = 0; i < L; ++i) {
        int mode = (i == L - 1) ? 1 : 0;
        fused_kernel<<<fgrid, 256, 0, stream>>>(hin[i], rowse, col, (const i32x4*)rowhead,
                                                W1L + (size_t)i * 16384, W2L + (size_t)i * 16384,
                                                b1 + i * D, b2 + i * D, hout[i], (float*)d_out,
                                                mode, ntiles, N);
    }
}

// Round 6
// 406.786 us; speedup vs baseline: 1.0924x; 1.0924x over previous
//
#include <hip/hip_runtime.h>
#include <hip/hip_bf16.h>

#define D 128
#define NBUCK_SHIFT 9
#define PAD_SLACK 2048   // per-bucket overflow slack (needs ~1800 avg)

typedef __bf16 bf16x8 __attribute__((ext_vector_type(8)));
typedef float f32x4 __attribute__((ext_vector_type(4)));
typedef float f32x2 __attribute__((ext_vector_type(2)));
typedef int i32x4 __attribute__((ext_vector_type(4)));
typedef int i32x2 __attribute__((ext_vector_type(2)));
typedef unsigned int u32x4 __attribute__((ext_vector_type(4)));
typedef unsigned short u16x4_t __attribute__((ext_vector_type(4)));
typedef unsigned short u16x8_t __attribute__((ext_vector_type(8)));

__device__ __forceinline__ unsigned short f2b(float f) {
    __hip_bfloat16 h = __float2bfloat16(f);
    return __builtin_bit_cast(unsigned short, h);
}

// accumulate 8 bf16 (as 4 u32) into 4 f32x2 accumulators; f32x2 += invites v_pk_add_f32
__device__ __forceinline__ void acc8(f32x2* acc, u32x4 x) {
#pragma unroll
    for (int r = 0; r < 4; ++r) {
        f32x2 t;
        t[0] = __builtin_bit_cast(float, x[r] << 16);
        t[1] = __builtin_bit_cast(float, x[r] & 0xffff0000u);
        acc[r] += t;
    }
}

// ---------------- CSR build (bucket-local, no per-node global atomics) ----------------
// Phase A: coarse histogram over nbuck (<=256) dst-buckets, LDS-aggregated.
__global__ __launch_bounds__(256) void coarse_hist_kernel(
        const int* __restrict__ dst, int* __restrict__ bco, int E, int nbuck) {
    __shared__ int s[256];
    int t = threadIdx.x;
    s[t] = 0;
    __syncthreads();
    for (int i = blockIdx.x * 256 + t; i < E; i += gridDim.x * 256)
        atomicAdd(&s[dst[i] >> NBUCK_SHIFT], 1);
    __syncthreads();
    if (t < nbuck && s[t] > 0) atomicAdd(&bco[t], s[t]);
}

// Phase B: exclusive scan of bucket counts -> bbase[0..nbuck], bbase[nbuck]=E. One block.
__global__ __launch_bounds__(256) void bucket_scan_kernel(
        const int* __restrict__ bco, int* __restrict__ bbase, int nbuck, int E) {
    __shared__ int s[256];
    int t = threadIdx.x;
    int c = (t < nbuck) ? bco[t] : 0;
    s[t] = c;
    __syncthreads();
    for (int o = 1; o < 256; o <<= 1) {
        int y = (t >= o) ? s[t - o] : 0;
        __syncthreads();
        s[t] += y;
        __syncthreads();
    }
    if (t < nbuck) bbase[t] = s[t] - c;
    if (t == 0) bbase[nbuck] = E;
}

// Phase C: partition edges into dst-bucket-grouped packed records (src<<9 | dst&511).
__global__ __launch_bounds__(256) void bucket_kernel(
        const int* __restrict__ src, const int* __restrict__ dst,
        const int* __restrict__ bbase, int* __restrict__ bcursor,
        unsigned int* __restrict__ pairs, int E, int nbuck) {
    __shared__ int lcnt[256];
    __shared__ int lbase[256];
    int t = threadIdx.x;
    int base = blockIdx.x * 4096;
    if (t < nbuck) lcnt[t] = 0;
    __syncthreads();
    int d[16], s[16];
#pragma unroll
    for (int k = 0; k < 16; ++k) {
        int i = base + t + k * 256;
        if (i < E) {
            d[k] = dst[i];
            s[k] = src[i];
            atomicAdd(&lcnt[d[k] >> NBUCK_SHIFT], 1);
        } else {
            d[k] = -1;
            s[k] = 0;
        }
    }
    __syncthreads();
    if (t < nbuck) {
        int c = lcnt[t];
        int g = (c > 0) ? atomicAdd(&bcursor[t], c) : 0;
        lbase[t] = bbase[t] + g;
        lcnt[t] = 0;
    }
    __syncthreads();
#pragma unroll
    for (int k = 0; k < 16; ++k) {
        if (d[k] >= 0) {
            int b = d[k] >> NBUCK_SHIFT;
            int r = atomicAdd(&lcnt[b], 1);
            pairs[lbase[b] + r] = ((unsigned)s[k] << 9) | ((unsigned)d[k] & 511u);
        }
    }
}

// Phase D: per-bucket LDS histogram + scan.
// rowhead[N][16] = {self, first 15 neighbors, zero-row dummies} as byte offsets (row*256).
// Overflow (deg>15) -> padded CSR windows (rowse = {start,end}, multiple of 4, 16B-aligned).
__global__ __launch_bounds__(1024) void bucket_build_kernel(
        const unsigned int* __restrict__ pairs, const int* __restrict__ bbase,
        i32x2* __restrict__ rowse, int* __restrict__ col, int* __restrict__ rowhead,
        int N, int E) {
    __shared__ int cnt[512];
    __shared__ int off[512];
    int t = threadIdx.x;
    int b = blockIdx.x;
    int s0 = bbase[b], s1 = bbase[b + 1];
    int p0 = ((s0 + 3) & ~3) + b * PAD_SLACK;   // overflow window base (16B aligned)
    if (t < 512) cnt[t] = 0;
    __syncthreads();
    for (int i = s0 + t; i < s1; i += 1024)
        atomicAdd(&cnt[pairs[i] & 511u], 1);
    __syncthreads();
    int deg = (t < 512) ? cnt[t] : 0;
    int ovp = (deg > 15) ? ((deg - 15 + 3) & ~3) : 0;   // padded overflow count
    if (t < 512) off[t] = ovp;
    __syncthreads();
    for (int o = 1; o < 512; o <<= 1) {
        int y = (t < 512 && t >= o) ? off[t - o] : 0;
        __syncthreads();
        if (t < 512) off[t] += y;
        __syncthreads();
    }
    int v0 = b << NBUCK_SHIFT;
    int zoff = N << 8;                          // byte offset of the all-zero row
    if (t < 512) {
        int ex = off[t] - ovp;                  // exclusive overflow prefix
        off[t] = ex;
        cnt[t] = 0;
        int v = v0 + t;
        if (v < N) {
            i32x2 se;
            se[0] = p0 + ex;
            se[1] = p0 + ex + ovp;
            rowse[v] = se;
            int* rhv = rowhead + (size_t)v * 16;
            rhv[0] = v << 8;                    // self-loop slot
            int ninl = deg < 15 ? deg : 15;
            for (int q = 1 + ninl; q < 16; ++q) rhv[q] = zoff;
        }
    }
    __syncthreads();
    for (int i = s0 + t; i < s1; i += 1024) {
        unsigned int p = pairs[i];
        int li = (int)(p & 511u);
        int x = (int)(p >> 9);
        int s = atomicAdd(&cnt[li], 1);
        if (s < 15) rowhead[(size_t)(v0 + li) * 16 + 1 + s] = x << 8;
        else        col[p0 + off[li] + (s - 15)] = x << 8;
    }
    __syncthreads();
    if (t < 512) {
        int cc = cnt[t];                        // == deg
        int ovreal = (cc > 15) ? cc - 15 : 0;
        int base2 = p0 + off[t];
        int endp = base2 + ((ovreal + 3) & ~3);
        for (int q = base2 + ovreal; q < endp; ++q) col[q] = zoff;
    }
}

// ---------------- dtype conversion ----------------
__global__ void f32_to_bf16_kernel(const float4* __restrict__ in, ushort4* __restrict__ out, int n4) {
    int i = blockIdx.x * blockDim.x + threadIdx.x;
    if (i < n4) {
        float4 f = in[i];
        ushort4 o;
        o.x = f2b(f.x); o.y = f2b(f.y); o.z = f2b(f.z); o.w = f2b(f.w);
        out[i] = o;
    }
}

// W[l][k][n] row-major -> frag-blocked bf16 for use as MFMA A-operand (swapped GEMM):
// flat short idx = ((l*32 + nt*4 + kb)*64 + lg*16 + l15)*8 + j holds W[k=kb*32+lg*8+j][n=nt*16+l15]
__global__ void wtrans_kernel(const float* __restrict__ W1, const float* __restrict__ W2,
                              unsigned short* __restrict__ W1L, unsigned short* __restrict__ W2L,
                              int total) {
    int i = blockIdx.x * blockDim.x + threadIdx.x;
    if (i < total) {
        int l = i >> 14;
        int rem = i & 16383;
        int k = rem >> 7;
        int n = rem & 127;
        int nt = n >> 4, l15 = n & 15;
        int kb = k >> 5, lg = (k >> 3) & 3, j = k & 7;
        int o = ((l * 32 + nt * 4 + kb) * 64 + lg * 16 + l15) * 8 + j;
        W1L[o] = f2b(W1[i]);
        W2L[o] = f2b(W2[i]);
    }
}

// ---------------- FUSED layer: 2 adjacent tiles / 512-thread block ----------------
// 8 waves; wave w owns output quadrant nt=w for BOTH tiles -> W fragments (8 x bf16x8
// = 32 VGPR) loaded ONCE per block, pinned in VGPRs via asm so LLVM can't re-sink the
// loads; their latency hides under the agg phase.
// Phase 1 (agg): wave w aggregates nodes m=w*4..w*4+3 of the 32 (tile = m>>4) into
//   LDS rstile (row stride 136 shorts = 272B -> conflict-minimal b128 reads).
// Phase 2 (GEMM1): per tile, acc = sum_kb mfma(W1[nt=w][kb], rst[tile][kb]) -> h1buf.
// Phase 3 (GEMM2): per tile, acc = sum_kb mfma(W2[nt=w][kb], h1[tile][kb]) -> out.
#define RSTRIDE 136
__global__ __launch_bounds__(512, 4) void fused_kernel(
        const unsigned short* __restrict__ h, const i32x2* __restrict__ rowse,
        const int* __restrict__ col, const i32x4* __restrict__ rowhead,
        const unsigned short* __restrict__ W1L, const unsigned short* __restrict__ W2L,
        const float* __restrict__ b1, const float* __restrict__ b2,
        unsigned short* __restrict__ hOut, float* __restrict__ fOut,
        int mode, int ntiles, int N) {
    __shared__ float b1s[128], b2s[128];
    __shared__ unsigned short rstile[2][16 * RSTRIDE];
    __shared__ unsigned short h1buf[2][2560];
    int tid = threadIdx.x;
    if (tid < 128) b1s[tid] = b1[tid];
    else if (tid < 256) b2s[tid - 128] = b2[tid - 128];
    int wave = tid >> 6, lane = tid & 63;
    int l15 = lane & 15, lg = lane >> 4;
    int tile0 = blockIdx.x * 2;

    // ---- preload this wave's W fragments (nt = wave), pin in VGPRs ----
    u32x4 w1u[4], w2u[4];
#pragma unroll
    for (int kb = 0; kb < 4; ++kb) {
        w1u[kb] = *(const u32x4*)(W1L + ((wave * 4 + kb) * 64 + lane) * 8);
        w2u[kb] = *(const u32x4*)(W2L + ((wave * 4 + kb) * 64 + lane) * 8);
    }
#pragma unroll
    for (int kb = 0; kb < 4; ++kb)
        asm volatile("" : "+v"(w1u[kb]), "+v"(w2u[kb]));

    const char* __restrict__ hb = (const char*)h;

    // ---------- phase 1: aggregation (wave w -> 4 of the block's 32 nodes) ----------
    {
        int i = lane & 15;           // feature block (16B)
        int j = lane >> 4;           // edge-slot group
        unsigned ioff = (unsigned)i * 16u;
        for (int q = 0; q < 4; ++q) {
            int m = wave * 4 + q;                 // 0..31
            int v = (tile0 << 4) + m;
            f32x2 accA[4], accB[4], accC[4], accD[4];
#pragma unroll
            for (int r = 0; r < 4; ++r) {
                accA[r] = (f32x2){0.f, 0.f};
                accB[r] = (f32x2){0.f, 0.f};
                accC[r] = (f32x2){0.f, 0.f};
                accD[r] = (f32x2){0.f, 0.f};
            }
            if (v < N) {
                i32x4 c4 = __builtin_nontemporal_load(&rowhead[(size_t)v * 4 + j]);
                i32x2 se = __builtin_nontemporal_load(&rowse[v]);
                u32x4 x0 = *(const u32x4*)(hb + ((unsigned)c4[0] + ioff));
                u32x4 x1 = *(const u32x4*)(hb + ((unsigned)c4[1] + ioff));
                u32x4 x2 = *(const u32x4*)(hb + ((unsigned)c4[2] + ioff));
                u32x4 x3 = *(const u32x4*)(hb + ((unsigned)c4[3] + ioff));
                int e = se[0] + 4 * j;
                int e1 = se[1];
                bool have = (e < e1);
                i32x4 o4;
                if (have) o4 = __builtin_nontemporal_load((const i32x4*)(col + e));
                acc8(accA, x0);
                acc8(accB, x1);
                acc8(accC, x2);
                acc8(accD, x3);
                while (have) {
                    int en = e + 16;
                    bool haven = (en < e1);
                    i32x4 o4n;
                    if (haven) o4n = __builtin_nontemporal_load((const i32x4*)(col + en));
                    u32x4 y0 = *(const u32x4*)(hb + ((unsigned)o4[0] + ioff));
                    u32x4 y1 = *(const u32x4*)(hb + ((unsigned)o4[1] + ioff));
                    u32x4 y2 = *(const u32x4*)(hb + ((unsigned)o4[2] + ioff));
                    u32x4 y3 = *(const u32x4*)(hb + ((unsigned)o4[3] + ioff));
                    acc8(accA, y0);
                    acc8(accB, y1);
                    acc8(accC, y2);
                    acc8(accD, y3);
                    o4 = o4n;
                    e = en;
                    have = haven;
                }
            }
            unsigned short outv[8];
#pragma unroll
            for (int r = 0; r < 4; ++r) {
                f32x2 s = (accA[r] + accB[r]) + (accC[r] + accD[r]);
                float lo = s[0], hi = s[1];
                lo += __shfl_xor(lo, 16);
                lo += __shfl_xor(lo, 32);
                hi += __shfl_xor(hi, 16);
                hi += __shfl_xor(hi, 32);
                outv[2 * r] = f2b(lo);
                outv[2 * r + 1] = f2b(hi);
            }
            if (j == 0) {
                u16x8_t o;
#pragma unroll
                for (int r = 0; r < 8; ++r) o[r] = outv[r];
                *(u16x8_t*)(rstile[m >> 4] + (m & 15) * RSTRIDE + i * 8) = o;
            }
        }
    }
    __syncthreads();

    // ---------- phase 2: GEMM1 for both tiles (wave's nt = wave) ----------
    {
        f32x4 acc[2];
#pragma unroll
        for (int t = 0; t < 2; ++t) acc[t] = (f32x4){0.f, 0.f, 0.f, 0.f};
#pragma unroll
        for (int kb = 0; kb < 4; ++kb) {
            bf16x8 wf = __builtin_bit_cast(bf16x8, w1u[kb]);
#pragma unroll
            for (int t = 0; t < 2; ++t) {
                bf16x8 bfrag = *(const bf16x8*)(rstile[t] + l15 * RSTRIDE + lg * 8 + kb * 32);
                acc[t] = __builtin_amdgcn_mfma_f32_16x16x32_bf16(wf, bfrag, acc[t], 0, 0, 0);
            }
        }
        int nt = wave;
        f32x4 bias = *(const f32x4*)(b1s + nt * 16 + lg * 4);
        int kb2 = nt >> 1;
        int lgk = (nt & 1) * 2 + (lg >> 1);
        int U = kb2 * 80 + l15 * 5 + lgk;
#pragma unroll
        for (int t = 0; t < 2; ++t) {
            u16x4_t o;
#pragma unroll
            for (int r = 0; r < 4; ++r) {
                float x = acc[t][r] + bias[r];
                if (mode == 0) x = fmaxf(x, 0.f);
                o[r] = f2b(x);
            }
            *(u16x4_t*)(h1buf[t] + U * 8 + (lg & 1) * 4) = o;
        }
    }
    __syncthreads();

    // ---------- phase 3: GEMM2 for both tiles ----------
    {
        f32x4 acc[2];
#pragma unroll
        for (int t = 0; t < 2; ++t) acc[t] = (f32x4){0.f, 0.f, 0.f, 0.f};
#pragma unroll
        for (int kb = 0; kb < 4; ++kb) {
            bf16x8 wf = __builtin_bit_cast(bf16x8, w2u[kb]);
#pragma unroll
            for (int t = 0; t < 2; ++t) {
                bf16x8 bf2 = *(const bf16x8*)(h1buf[t] + (kb * 80 + l15 * 5 + lg) * 8);
                acc[t] = __builtin_amdgcn_mfma_f32_16x16x32_bf16(wf, bf2, acc[t], 0, 0, 0);
            }
        }
        int nt = wave;
        f32x4 bias = *(const f32x4*)(b2s + nt * 16 + lg * 4);
        int c0 = nt * 16 + lg * 4;
#pragma unroll
        for (int t = 0; t < 2; ++t) {
            int m = ((tile0 + t) << 4) + l15;
            if (m < N) {
                if (mode == 0) {
                    u16x4_t o;
#pragma unroll
                    for (int r = 0; r < 4; ++r) o[r] = f2b(fmaxf(acc[t][r] + bias[r], 0.f));
                    *(u16x4_t*)(hOut + (size_t)m * D + c0) = o;
                } else {
                    f32x4 o;
#pragma unroll
                    for (int r = 0; r < 4; ++r) o[r] = acc[t][r] + bias[r];
                    *(f32x4*)(fOut + (size_t)m * D + c0) = o;
                }
            }
        }
    }
}

extern "C" void kernel_launch(void* const* d_in, const int* in_sizes, int n_in,
                              void* d_out, int out_size, void* d_ws, size_t ws_size,
                              hipStream_t stream) {
    const float* feat = (const float*)d_in[0];
    const float* W1 = (const float*)d_in[1];
    const float* b1 = (const float*)d_in[2];
    const float* W2 = (const float*)d_in[3];
    const float* b2 = (const float*)d_in[4];
    const int* src = (const int*)d_in[5];
    const int* dst = (const int*)d_in[6];

    const int N = in_sizes[0] / D;
    const int L = in_sizes[2] / D;
    const int E = in_sizes[5];

    char* w = (char*)d_ws;
    size_t off = 0;
    auto alloc = [&](size_t bytes) {
        void* p = w + off;
        off = (off + bytes + 255) & ~(size_t)255;
        return p;
    };
    // +1 row on h buffers: row N is the all-zero row that dummy (padding) slots read.
    unsigned short* bufA = (unsigned short*)alloc((size_t)(N + 1) * D * 2);
    unsigned short* bufB = (unsigned short*)alloc((size_t)(N + 1) * D * 2);
    unsigned int* pairs = (unsigned int*)alloc((size_t)E * 4);
    int* col = (int*)alloc(((size_t)E + 256 * PAD_SLACK + 16) * 4);
    int* rowhead = (int*)alloc((size_t)N * 16 * 4);
    i32x2* rowse = (i32x2*)alloc((size_t)N * 8);
    int* bco = (int*)alloc(512 * 4);       // bco[256] + bcursor[256]
    int* bcursor = bco + 256;
    int* bbase = (int*)alloc(257 * 4);
    unsigned short* W1L = (unsigned short*)alloc((size_t)L * 16384 * 2);
    unsigned short* W2L = (unsigned short*)alloc((size_t)L * 16384 * 2);

    int nbuck = (N + (1 << NBUCK_SHIFT) - 1) >> NBUCK_SHIFT;

    // CSR build — bucket-local, rowhead + overflow CSR
    hipMemsetAsync(bco, 0, 512 * 4, stream);
    hipMemsetAsync(bufA + (size_t)N * D, 0, D * 2, stream);
    hipMemsetAsync(bufB + (size_t)N * D, 0, D * 2, stream);
    coarse_hist_kernel<<<512, 256, 0, stream>>>(dst, bco, E, nbuck);
    bucket_scan_kernel<<<1, 256, 0, stream>>>(bco, bbase, nbuck, E);
    bucket_kernel<<<(E + 4095) / 4096, 256, 0, stream>>>(src, dst, bbase, bcursor, pairs, E, nbuck);
    bucket_build_kernel<<<nbuck, 1024, 0, stream>>>(pairs, bbase, rowse, col, rowhead, N, E);

    // dtype prep
    int n4 = N * D / 4;
    f32_to_bf16_kernel<<<(n4 + 255) / 256, 256, 0, stream>>>((const float4*)feat, (ushort4*)bufA, n4);
    int wtotal = L * D * D;
    wtrans_kernel<<<(wtotal + 255) / 256, 256, 0, stream>>>(W1, W2, W1L, W2L, wtotal);

    int ntiles = (N + 15) / 16;
    int fgrid = (ntiles + 1) / 2;
    const unsigned short* hin[3] = {bufA, bufB, bufA};
    unsigned short* hout[3] = {bufB, bufA, nullptr};
    for (int i = 0; i < L; ++i) {
        int mode = (i == L - 1) ? 1 : 0;
        fused_kernel<<<fgrid, 512, 0, stream>>>(hin[i], rowse, col, (const i32x4*)rowhead,
                                                W1L + (size_t)i * 16384, W2L + (size_t)i * 16384,
                                                b1 + i * D, b2 + i * D, hout[i], (float*)d_out,
                                                mode, ntiles, N);
    }
}

// Round 7
// 390.058 us; speedup vs baseline: 1.1393x; 1.0429x over previous
//
#include <hip/hip_runtime.h>
#include <hip/hip_bf16.h>

#define D 128
#define NBUCK_SHIFT 9
#define PAD_SLACK 2048   // per-bucket overflow slack (needs ~1800 avg)

typedef __bf16 bf16x8 __attribute__((ext_vector_type(8)));
typedef float f32x4 __attribute__((ext_vector_type(4)));
typedef float f32x2 __attribute__((ext_vector_type(2)));
typedef int i32x4 __attribute__((ext_vector_type(4)));
typedef int i32x2 __attribute__((ext_vector_type(2)));
typedef unsigned int u32x4 __attribute__((ext_vector_type(4)));
typedef unsigned short u16x4_t __attribute__((ext_vector_type(4)));
typedef unsigned short u16x8_t __attribute__((ext_vector_type(8)));

__device__ __forceinline__ unsigned short f2b(float f) {
    __hip_bfloat16 h = __float2bfloat16(f);
    return __builtin_bit_cast(unsigned short, h);
}

// accumulate 8 bf16 (as 4 u32) into 4 f32x2 accumulators; f32x2 += invites v_pk_add_f32
__device__ __forceinline__ void acc8(f32x2* acc, u32x4 x) {
#pragma unroll
    for (int r = 0; r < 4; ++r) {
        f32x2 t;
        t[0] = __builtin_bit_cast(float, x[r] << 16);
        t[1] = __builtin_bit_cast(float, x[r] & 0xffff0000u);
        acc[r] += t;
    }
}

// ---------------- prep: f32->bf16 cast + W frag-block + zero-init (one launch) ----------------
// Role-split by blockIdx: [0,nCast) cast feat; [nCast,nCast+nW) wtrans; last block zeroes
// bco/bcursor and the zero-rows of bufA/bufB.
// wtrans layout: flat short idx = ((l*32 + nt*4 + kb)*64 + lg*16 + l15)*8 + j holds
// W[k=kb*32+lg*8+j][n=nt*16+l15]
__global__ __launch_bounds__(256) void prep_kernel(
        const float4* __restrict__ feat4, ushort4* __restrict__ outA, int n4,
        const float* __restrict__ W1, const float* __restrict__ W2,
        unsigned short* __restrict__ W1L, unsigned short* __restrict__ W2L, int wtotal,
        int* __restrict__ bco, unsigned short* __restrict__ bufA,
        unsigned short* __restrict__ bufB, int N) {
    int b = blockIdx.x;
    int t = threadIdx.x;
    int nCast = (n4 + 255) >> 8;
    int nW = (wtotal + 255) >> 8;
    if (b < nCast) {
        int i = b * 256 + t;
        if (i < n4) {
            float4 f = feat4[i];
            ushort4 o;
            o.x = f2b(f.x); o.y = f2b(f.y); o.z = f2b(f.z); o.w = f2b(f.w);
            outA[i] = o;
        }
    } else if (b < nCast + nW) {
        int i = (b - nCast) * 256 + t;
        if (i < wtotal) {
            int l = i >> 14;
            int rem = i & 16383;
            int k = rem >> 7;
            int n = rem & 127;
            int nt = n >> 4, l15 = n & 15;
            int kb = k >> 5, lg = (k >> 3) & 3, j = k & 7;
            int o = ((l * 32 + nt * 4 + kb) * 64 + lg * 16 + l15) * 8 + j;
            W1L[o] = f2b(W1[i]);
            W2L[o] = f2b(W2[i]);
        }
    } else {
        bco[t] = 0;
        bco[t + 256] = 0;      // bcursor
        if (t < 128) {
            bufA[(size_t)N * D + t] = 0;
            bufB[(size_t)N * D + t] = 0;
        }
    }
}

// ---------------- CSR build (bucket-local, no per-node global atomics) ----------------
// Phase A: coarse histogram over nbuck (<=256) dst-buckets, LDS-aggregated.
__global__ __launch_bounds__(256) void coarse_hist_kernel(
        const int* __restrict__ dst, int* __restrict__ bco, int E, int nbuck) {
    __shared__ int s[256];
    int t = threadIdx.x;
    s[t] = 0;
    __syncthreads();
    for (int i = blockIdx.x * 256 + t; i < E; i += gridDim.x * 256)
        atomicAdd(&s[dst[i] >> NBUCK_SHIFT], 1);
    __syncthreads();
    if (t < nbuck && s[t] > 0) atomicAdd(&bco[t], s[t]);
}

// Phase C: partition edges into dst-bucket-grouped packed records (src<<9 | dst&511).
// Bucket bases derived locally from bco via LDS scan (no separate scan kernel).
__global__ __launch_bounds__(256) void bucket_kernel(
        const int* __restrict__ src, const int* __restrict__ dst,
        const int* __restrict__ bco, int* __restrict__ bcursor,
        unsigned int* __restrict__ pairs, int E, int nbuck) {
    __shared__ int lcnt[256];
    __shared__ int lbase[256];
    int t = threadIdx.x;
    int base = blockIdx.x * 4096;
    // local exclusive-prefix of bco -> ebase (bco[t]=0 for t>=nbuck, zeroed in prep)
    int c0 = bco[t];
    lbase[t] = c0;
    __syncthreads();
    for (int o = 1; o < 256; o <<= 1) {
        int y = (t >= o) ? lbase[t - o] : 0;
        __syncthreads();
        lbase[t] += y;
        __syncthreads();
    }
    int ebase = lbase[t] - c0;
    __syncthreads();
    if (t < nbuck) lcnt[t] = 0;
    __syncthreads();
    int d[16], s[16];
#pragma unroll
    for (int k = 0; k < 16; ++k) {
        int i = base + t + k * 256;
        if (i < E) {
            d[k] = dst[i];
            s[k] = src[i];
            atomicAdd(&lcnt[d[k] >> NBUCK_SHIFT], 1);
        } else {
            d[k] = -1;
            s[k] = 0;
        }
    }
    __syncthreads();
    if (t < nbuck) {
        int c = lcnt[t];
        int g = (c > 0) ? atomicAdd(&bcursor[t], c) : 0;
        lbase[t] = ebase + g;
        lcnt[t] = 0;
    }
    __syncthreads();
#pragma unroll
    for (int k = 0; k < 16; ++k) {
        if (d[k] >= 0) {
            int b = d[k] >> NBUCK_SHIFT;
            int r = atomicAdd(&lcnt[b], 1);
            pairs[lbase[b] + r] = ((unsigned)s[k] << 9) | ((unsigned)d[k] & 511u);
        }
    }
}

// Phase D: per-bucket LDS histogram + scan.
// rowhead[N][16] = {self, first 15 neighbors, zero-row dummies} as byte offsets (row*256).
// Overflow (deg>15) -> padded CSR windows (rowse = {start,end}, multiple of 4, 16B-aligned).
// Bucket edge range [s0,s1) derived locally from bco via LDS scan.
__global__ __launch_bounds__(1024) void bucket_build_kernel(
        const unsigned int* __restrict__ pairs, const int* __restrict__ bco,
        i32x2* __restrict__ rowse, int* __restrict__ col, int* __restrict__ rowhead,
        int N, int E) {
    __shared__ int cnt[512];
    __shared__ int off[512];
    __shared__ int s01[2];
    int t = threadIdx.x;
    int b = blockIdx.x;
    // local prefix of bco over 256 buckets -> this bucket's edge window
    if (t < 256) off[t] = bco[t];
    __syncthreads();
    for (int o = 1; o < 256; o <<= 1) {
        int y = (t < 256 && t >= o) ? off[t - o] : 0;
        __syncthreads();
        if (t < 256) off[t] += y;
        __syncthreads();
    }
    if (t == 0) {
        s01[1] = off[b];
        s01[0] = off[b] - bco[b];
    }
    __syncthreads();
    int s0 = s01[0], s1 = s01[1];
    int p0 = ((s0 + 3) & ~3) + b * PAD_SLACK;   // overflow window base (16B aligned)
    if (t < 512) cnt[t] = 0;
    __syncthreads();
    for (int i = s0 + t; i < s1; i += 1024)
        atomicAdd(&cnt[pairs[i] & 511u], 1);
    __syncthreads();
    int deg = (t < 512) ? cnt[t] : 0;
    int ovp = (deg > 15) ? ((deg - 15 + 3) & ~3) : 0;   // padded overflow count
    if (t < 512) off[t] = ovp;
    __syncthreads();
    for (int o = 1; o < 512; o <<= 1) {
        int y = (t < 512 && t >= o) ? off[t - o] : 0;
        __syncthreads();
        if (t < 512) off[t] += y;
        __syncthreads();
    }
    int v0 = b << NBUCK_SHIFT;
    int zoff = N << 8;                          // byte offset of the all-zero row
    if (t < 512) {
        int ex = off[t] - ovp;                  // exclusive overflow prefix
        off[t] = ex;
        cnt[t] = 0;
        int v = v0 + t;
        if (v < N) {
            i32x2 se;
            se[0] = p0 + ex;
            se[1] = p0 + ex + ovp;
            rowse[v] = se;
            int* rhv = rowhead + (size_t)v * 16;
            rhv[0] = v << 8;                    // self-loop slot
            int ninl = deg < 15 ? deg : 15;
            for (int q = 1 + ninl; q < 16; ++q) rhv[q] = zoff;
        }
    }
    __syncthreads();
    for (int i = s0 + t; i < s1; i += 1024) {
        unsigned int p = pairs[i];
        int li = (int)(p & 511u);
        int x = (int)(p >> 9);
        int s = atomicAdd(&cnt[li], 1);
        if (s < 15) rowhead[(size_t)(v0 + li) * 16 + 1 + s] = x << 8;
        else        col[p0 + off[li] + (s - 15)] = x << 8;
    }
    __syncthreads();
    if (t < 512) {
        int cc = cnt[t];                        // == deg
        int ovreal = (cc > 15) ? cc - 15 : 0;
        int base2 = p0 + off[t];
        int endp = base2 + ((ovreal + 3) & ~3);
        for (int q = base2 + ovreal; q < endp; ++q) col[q] = zoff;
    }
}

// ---------------- FUSED layer: agg (gather+sum) -> LDS tile -> 2-GEMM MLP ----------------
// (R4 structure: one 16-node tile per 256-thread block, dispatch-ordered, W from L2.)
// Phase 1 (agg): wave w aggregates nodes v0+4w..v0+4w+3 into LDS rstile (row stride
//   136 shorts = 272B: b128 reads spread to 8 words/bank, conflict-minimal).
// Phase 2 (mlp): waves split the 8 nt output quadrants 2-each; h1 staged in shared
//   padded buffer (per-wave kb2 = wave regions disjoint).
#define RSTRIDE 136
__global__ __launch_bounds__(256, 4) void fused_kernel(
        const unsigned short* __restrict__ h, const i32x2* __restrict__ rowse,
        const int* __restrict__ col, const i32x4* __restrict__ rowhead,
        const unsigned short* __restrict__ W1L, const unsigned short* __restrict__ W2L,
        const float* __restrict__ b1, const float* __restrict__ b2,
        unsigned short* __restrict__ hOut, float* __restrict__ fOut,
        int mode, int ntiles, int N) {
    __shared__ float b1s[128], b2s[128];
    __shared__ unsigned short rstile[16 * RSTRIDE];
    __shared__ unsigned short h1buf[2560];
    int tid = threadIdx.x;
    if (tid < 128) b1s[tid] = b1[tid];
    else b2s[tid - 128] = b2[tid - 128];
    int wave = tid >> 6, lane = tid & 63;
    int v0 = blockIdx.x << 4;

    // ---------- phase 1: aggregation ----------
    {
        int i = lane & 15;           // feature block (16B)
        int j = lane >> 4;           // edge-slot group
        const char* __restrict__ hb = (const char*)h;
        unsigned ioff = (unsigned)i * 16u;
        for (int q = 0; q < 4; ++q) {
            int m = wave * 4 + q;
            int v = v0 + m;
            f32x2 accA[4], accB[4], accC[4], accD[4];
#pragma unroll
            for (int r = 0; r < 4; ++r) {
                accA[r] = (f32x2){0.f, 0.f};
                accB[r] = (f32x2){0.f, 0.f};
                accC[r] = (f32x2){0.f, 0.f};
                accD[r] = (f32x2){0.f, 0.f};
            }
            if (v < N) {
                i32x4 c4 = __builtin_nontemporal_load(&rowhead[(size_t)v * 4 + j]);
                i32x2 se = __builtin_nontemporal_load(&rowse[v]);
                u32x4 x0 = *(const u32x4*)(hb + ((unsigned)c4[0] + ioff));
                u32x4 x1 = *(const u32x4*)(hb + ((unsigned)c4[1] + ioff));
                u32x4 x2 = *(const u32x4*)(hb + ((unsigned)c4[2] + ioff));
                u32x4 x3 = *(const u32x4*)(hb + ((unsigned)c4[3] + ioff));
                int e = se[0] + 4 * j;
                int e1 = se[1];
                bool have = (e < e1);
                i32x4 o4;
                if (have) o4 = __builtin_nontemporal_load((const i32x4*)(col + e));
                acc8(accA, x0);
                acc8(accB, x1);
                acc8(accC, x2);
                acc8(accD, x3);
                while (have) {
                    int en = e + 16;
                    bool haven = (en < e1);
                    i32x4 o4n;
                    if (haven) o4n = __builtin_nontemporal_load((const i32x4*)(col + en));
                    u32x4 y0 = *(const u32x4*)(hb + ((unsigned)o4[0] + ioff));
                    u32x4 y1 = *(const u32x4*)(hb + ((unsigned)o4[1] + ioff));
                    u32x4 y2 = *(const u32x4*)(hb + ((unsigned)o4[2] + ioff));
                    u32x4 y3 = *(const u32x4*)(hb + ((unsigned)o4[3] + ioff));
                    acc8(accA, y0);
                    acc8(accB, y1);
                    acc8(accC, y2);
                    acc8(accD, y3);
                    o4 = o4n;
                    e = en;
                    have = haven;
                }
            }
            unsigned short outv[8];
#pragma unroll
            for (int r = 0; r < 4; ++r) {
                f32x2 s = (accA[r] + accB[r]) + (accC[r] + accD[r]);
                float lo = s[0], hi = s[1];
                lo += __shfl_xor(lo, 16);
                lo += __shfl_xor(lo, 32);
                hi += __shfl_xor(hi, 16);
                hi += __shfl_xor(hi, 32);
                outv[2 * r] = f2b(lo);
                outv[2 * r + 1] = f2b(hi);
            }
            if (j == 0) {
                u16x8_t o;
#pragma unroll
                for (int r = 0; r < 8; ++r) o[r] = outv[r];
                *(u16x8_t*)(rstile + m * RSTRIDE + i * 8) = o;
            }
        }
    }
    __syncthreads();

    // ---------- phase 2: 2-GEMM MLP (wave handles nt = wave*2, wave*2+1) ----------
    int l15 = lane & 15, lg = lane >> 4;
    bf16x8 bfrag[4];
#pragma unroll
    for (int kb = 0; kb < 4; ++kb)
        bfrag[kb] = *(const bf16x8*)(rstile + l15 * RSTRIDE + lg * 8 + kb * 32);

    f32x4 acc[2];
#pragma unroll
    for (int t = 0; t < 2; ++t) acc[t] = (f32x4){0.f, 0.f, 0.f, 0.f};
#pragma unroll
    for (int kb = 0; kb < 4; ++kb)
#pragma unroll
        for (int t = 0; t < 2; ++t) {
            int nt = wave * 2 + t;
            bf16x8 wf = *(const bf16x8*)(W1L + ((nt * 4 + kb) * 64 + lane) * 8);
            acc[t] = __builtin_amdgcn_mfma_f32_16x16x32_bf16(wf, bfrag[kb], acc[t], 0, 0, 0);
        }
#pragma unroll
    for (int t = 0; t < 2; ++t) {
        int nt = wave * 2 + t;
        f32x4 bias = *(const f32x4*)(b1s + nt * 16 + lg * 4);
        int kb2 = nt >> 1;                    // == wave: per-wave disjoint h1 region
        int lgk = (nt & 1) * 2 + (lg >> 1);
        int U = kb2 * 80 + l15 * 5 + lgk;
        u16x4_t o;
#pragma unroll
        for (int r = 0; r < 4; ++r) {
            float x = acc[t][r] + bias[r];
            if (mode == 0) x = fmaxf(x, 0.f);
            o[r] = f2b(x);
        }
        *(u16x4_t*)(h1buf + U * 8 + (lg & 1) * 4) = o;
    }
    __syncthreads();
    bf16x8 bf2[4];
#pragma unroll
    for (int kb = 0; kb < 4; ++kb)
        bf2[kb] = *(const bf16x8*)(h1buf + (kb * 80 + l15 * 5 + lg) * 8);
#pragma unroll
    for (int t = 0; t < 2; ++t) acc[t] = (f32x4){0.f, 0.f, 0.f, 0.f};
#pragma unroll
    for (int kb = 0; kb < 4; ++kb)
#pragma unroll
        for (int t = 0; t < 2; ++t) {
            int nt = wave * 2 + t;
            bf16x8 wf = *(const bf16x8*)(W2L + ((nt * 4 + kb) * 64 + lane) * 8);
            acc[t] = __builtin_amdgcn_mfma_f32_16x16x32_bf16(wf, bf2[kb], acc[t], 0, 0, 0);
        }
    int m = v0 + l15;
    if (m < N) {
#pragma unroll
        for (int t = 0; t < 2; ++t) {
            int nt = wave * 2 + t;
            f32x4 bias = *(const f32x4*)(b2s + nt * 16 + lg * 4);
            int c0 = nt * 16 + lg * 4;
            if (mode == 0) {
                u16x4_t o;
#pragma unroll
                for (int r = 0; r < 4; ++r) o[r] = f2b(fmaxf(acc[t][r] + bias[r], 0.f));
                *(u16x4_t*)(hOut + (size_t)m * D + c0) = o;
            } else {
                f32x4 o;
#pragma unroll
                for (int r = 0; r < 4; ++r) o[r] = acc[t][r] + bias[r];
                *(f32x4*)(fOut + (size_t)m * D + c0) = o;
            }
        }
    }
}

extern "C" void kernel_launch(void* const* d_in, const int* in_sizes, int n_in,
                              void* d_out, int out_size, void* d_ws, size_t ws_size,
                              hipStream_t stream) {
    const float* feat = (const float*)d_in[0];
    const float* W1 = (const float*)d_in[1];
    const float* b1 = (const float*)d_in[2];
    const float* W2 = (const float*)d_in[3];
    const float* b2 = (const float*)d_in[4];
    const int* src = (const int*)d_in[5];
    const int* dst = (const int*)d_in[6];

    const int N = in_sizes[0] / D;
    const int L = in_sizes[2] / D;
    const int E = in_sizes[5];

    char* w = (char*)d_ws;
    size_t off = 0;
    auto alloc = [&](size_t bytes) {
        void* p = w + off;
        off = (off + bytes + 255) & ~(size_t)255;
        return p;
    };
    // +1 row on h buffers: row N is the all-zero row that dummy (padding) slots read.
    unsigned short* bufA = (unsigned short*)alloc((size_t)(N + 1) * D * 2);
    unsigned short* bufB = (unsigned short*)alloc((size_t)(N + 1) * D * 2);
    unsigned int* pairs = (unsigned int*)alloc((size_t)E * 4);
    int* col = (int*)alloc(((size_t)E + 256 * PAD_SLACK + 16) * 4);
    int* rowhead = (int*)alloc((size_t)N * 16 * 4);
    i32x2* rowse = (i32x2*)alloc((size_t)N * 8);
    int* bco = (int*)alloc(512 * 4);       // bco[256] + bcursor[256]
    int* bcursor = bco + 256;
    unsigned short* W1L = (unsigned short*)alloc((size_t)L * 16384 * 2);
    unsigned short* W2L = (unsigned short*)alloc((size_t)L * 16384 * 2);

    int nbuck = (N + (1 << NBUCK_SHIFT) - 1) >> NBUCK_SHIFT;

    // prep (cast + wtrans + zero-init), then CSR build
    int n4 = N * D / 4;
    int wtotal = L * D * D;
    int nCast = (n4 + 255) / 256;
    int nW = (wtotal + 255) / 256;
    prep_kernel<<<nCast + nW + 1, 256, 0, stream>>>(
        (const float4*)feat, (ushort4*)bufA, n4, W1, W2, W1L, W2L, wtotal,
        bco, bufA, bufB, N);
    coarse_hist_kernel<<<512, 256, 0, stream>>>(dst, bco, E, nbuck);
    bucket_kernel<<<(E + 4095) / 4096, 256, 0, stream>>>(src, dst, bco, bcursor, pairs, E, nbuck);
    bucket_build_kernel<<<nbuck, 1024, 0, stream>>>(pairs, bco, rowse, col, rowhead, N, E);

    int ntiles = (N + 15) / 16;
    const unsigned short* hin[3] = {bufA, bufB, bufA};
    unsigned short* hout[3] = {bufB, bufA, nullptr};
    for (int i = 0; i < L; ++i) {
        int mode = (i == L - 1) ? 1 : 0;
        fused_kernel<<<ntiles, 256, 0, stream>>>(hin[i], rowse, col, (const i32x4*)rowhead,
                                                 W1L + (size_t)i * 16384, W2L + (size_t)i * 16384,
                                                 b1 + i * D, b2 + i * D, hout[i], (float*)d_out,
                                                 mode, ntiles, N);
    }
}